// Round 5
// baseline (18.923 us; speedup 1.0000x reference)
//
#include <hip/hip_runtime.h>
#include <hip/hip_bf16.h>

#define NEGV (-1e9f)

typedef __attribute__((ext_vector_type(8))) short short8;
typedef __attribute__((ext_vector_type(4))) float f32x4;

#define MFMA16(a, b, c) __builtin_amdgcn_mfma_f32_16x16x32_bf16(a, b, c, 0, 0, 0)

__device__ __forceinline__ unsigned short f2bf(float x) {
    union { __hip_bfloat16 h; unsigned short u; } c;
    c.h = __float2bfloat16(x);
    return c.u;
}

__device__ __forceinline__ short8 pack2(f32x4 a, f32x4 b) {
    short8 r;
    r[0] = (short)f2bf(a[0]); r[1] = (short)f2bf(a[1]);
    r[2] = (short)f2bf(a[2]); r[3] = (short)f2bf(a[3]);
    r[4] = (short)f2bf(b[0]); r[5] = (short)f2bf(b[1]);
    r[6] = (short)f2bf(b[2]); r[7] = (short)f2bf(b[3]);
    return r;
}

__device__ __forceinline__ short8 pack8(const float* v) {
    short8 r;
#pragma unroll
    for (int i = 0; i < 8; ++i) r[i] = (short)f2bf(v[i]);
    return r;
}

// Single kernel, single barrier. 4 graphs per 256-thread block, grid = B/4
// (= 1024 blocks = exactly one resident round at 4 blocks/CU).
// A-operands (group rows, glob) are loaded straight from global into MFMA
// fragment registers (no staging LDS, no staging barrier). Weight B-fragments
// are gathered per-kt from L2-hot W1 (16-lane-coalesced 64B segments).
__global__ __launch_bounds__(256, 4) void dock_main(
    const float* __restrict__ nodes,   // [B*64,128]
    const float* __restrict__ glob,    // [B,128]
    const int*   __restrict__ dock,    // [B,64]
    const float* __restrict__ W1,      // [384,64]
    const float* __restrict__ b1,      // [64]
    const float* __restrict__ b2,      // [1]
    const float* __restrict__ W2,      // [64]
    float* __restrict__ out)           // [B,64]
{
    __shared__ float sPQ[32][132];     // 16.9 KB spill: PQ[row][n]
    __shared__ float sA[4][68];        // A[graph][n] (b1 folded)

    const int t    = threadIdx.x;
    const int lane = t & 63;
    const int w    = __builtin_amdgcn_readfirstlane(t >> 6);
    const int b0   = blockIdx.x * 4;
    const int lr   = lane & 15, lg = lane >> 4;

    // early independent loads (latency hidden under the gather/MFMA phase)
    const int idx = (b0 + w) * 64 + lane;
    const int dmask = dock[idx];
    const float b1v = b1[w * 16 + lr];
    const float b2v = b2[0];

    // A-fragment lane base pointers: lane l -> row (l&15) [+16], k-slice lg*8
    const float* pG0 = nodes + ((size_t)(b0 + (lr >> 3)) * 64 + (lr & 7)) * 128 + lg * 8;
    const float* pG1 = nodes + ((size_t)(b0 + 2 + (lr >> 3)) * 64 + (lr & 7)) * 128 + lg * 8;
    const float* pGl = glob + (size_t)(b0 + lr) * 128 + lg * 8;   // deref only if lr<4

    // weight gather bases (verified in r2/r3): col n, rows k (stride 64 floats)
    const int n0 = w * 32 + lr;
    const int n1 = n0 + 16;
    const float* Wp0 = (n0 < 64) ? W1 + 128 * 64 + n0 : W1 + 256 * 64 + (n0 - 64);
    const float* Wp1 = (n1 < 64) ? W1 + 128 * 64 + n1 : W1 + 256 * 64 + (n1 - 64);
    const float* Wpg = W1 + (w * 16 + lr);

    f32x4 acc00 = (f32x4)0.f, acc01 = (f32x4)0.f;
    f32x4 acc10 = (f32x4)0.f, acc11 = (f32x4)0.f;
    f32x4 accA  = (f32x4)0.f;

#pragma unroll
    for (int kt = 0; kt < 4; ++kt) {
        // ---- weight B-fragments for this kt (k = kt*32 + lg*8 + i)
        float v0[8], v1[8], vg[8];
#pragma unroll
        for (int i = 0; i < 8; ++i) {
            const int k = kt * 32 + lg * 8 + i;
            v0[i] = Wp0[k * 64];
            v1[i] = Wp1[k * 64];
            vg[i] = Wpg[k * 64];
        }
        // ---- A-fragments straight from global
        f32x4 a0l = *(const f32x4*)(pG0 + kt * 32);
        f32x4 a0h = *(const f32x4*)(pG0 + kt * 32 + 4);
        f32x4 a1l = *(const f32x4*)(pG1 + kt * 32);
        f32x4 a1h = *(const f32x4*)(pG1 + kt * 32 + 4);
        short8 aGl;
        if (lr < 4) {
            f32x4 gl_ = *(const f32x4*)(pGl + kt * 32);
            f32x4 gh_ = *(const f32x4*)(pGl + kt * 32 + 4);
            aGl = pack2(gl_, gh_);
        } else {
            aGl = (short8)0;
        }
        short8 aG0 = pack2(a0l, a0h);
        short8 aG1 = pack2(a1l, a1h);
        short8 bf0 = pack8(v0);
        short8 bf1 = pack8(v1);
        short8 bfg = pack8(vg);

        acc00 = MFMA16(aG0, bf0, acc00);
        acc01 = MFMA16(aG0, bf1, acc01);
        acc10 = MFMA16(aG1, bf0, acc10);
        acc11 = MFMA16(aG1, bf1, acc11);
        accA  = MFMA16(aGl, bfg, accA);
    }

    // ---- spill C fragments: C[row=(lane>>4)*4+r][col=lane&15]
#pragma unroll
    for (int r = 0; r < 4; ++r) {
        sPQ[lg * 4 + r][w * 32 + lr]           = acc00[r];
        sPQ[lg * 4 + r][w * 32 + 16 + lr]      = acc01[r];
        sPQ[16 + lg * 4 + r][w * 32 + lr]      = acc10[r];
        sPQ[16 + lg * 4 + r][w * 32 + 16 + lr] = acc11[r];
    }
    if (lg == 0) {
#pragma unroll
        for (int r = 0; r < 4; ++r)
            sA[r][w * 16 + lr] = accA[r] + b1v;   // graph r, hidden col w*16+lr
    }
    __syncthreads();   // the only barrier: spill -> cross-wave stage 2

    // ---- stage 2: wave w -> graph b0+w; lane p=(i,j)
    const int i = lane >> 3, j = lane & 7;
    const float* aRow = &sA[w][0];
    const float* pRow = &sPQ[w * 8 + i][0];       // P = cols [0,64)
    const float* qRow = &sPQ[w * 8 + j][64];      // Q = cols [64,128)

    float s = 0.f;
#pragma unroll
    for (int kk = 0; kk < 64; kk += 4) {
        f32x4 a4 = *(const f32x4*)(aRow + kk);
        f32x4 p4 = *(const f32x4*)(pRow + kk);
        f32x4 q4 = *(const f32x4*)(qRow + kk);
        f32x4 w4 = *(const f32x4*)(W2 + kk);
#pragma unroll
        for (int u = 0; u < 4; ++u) {
            float h = a4[u] + p4[u] + q4[u];      // b1 folded into A
            h = fmaxf(h, 0.f);
            s = fmaf(h, w4[u], s);
        }
    }
    s += b2v;

    out[idx] = ((i != j) && (dmask != 0)) ? s : NEGV;
}

extern "C" void kernel_launch(void* const* d_in, const int* in_sizes, int n_in,
                              void* d_out, int out_size, void* d_ws, size_t ws_size,
                              hipStream_t stream) {
    const float* nodes = (const float*)d_in[0];
    const float* glob  = (const float*)d_in[1];
    // d_in[2] group_mask_nodes, d_in[3] batch: unused (rows sorted, 8 group rows/graph)
    const int*   dock  = (const int*)d_in[4];
    const float* W1    = (const float*)d_in[5];
    const float* b1    = (const float*)d_in[6];
    const float* W2    = (const float*)d_in[7];
    const float* b2    = (const float*)d_in[8];
    float* out = (float*)d_out;

    const int B = in_sizes[1] / 128;   // 4096
    dock_main<<<dim3(B / 4), dim3(256), 0, stream>>>(
        nodes, glob, dock, W1, b1, b2, W2, out);
}

// Round 6
// 15.166 us; speedup vs baseline: 1.2478x; 1.2478x over previous
//
#include <hip/hip_runtime.h>
#include <hip/hip_bf16.h>

#define NEGV (-1e9f)

typedef __attribute__((ext_vector_type(8))) short short8;
typedef __attribute__((ext_vector_type(4))) float f32x4;

#define MFMA16(a, b, c) __builtin_amdgcn_mfma_f32_16x16x32_bf16(a, b, c, 0, 0, 0)

__device__ __forceinline__ unsigned short f2bf(float x) {
    union { __hip_bfloat16 h; unsigned short u; } c;
    c.h = __float2bfloat16(x);
    return c.u;
}

__device__ __forceinline__ short8 pack2(f32x4 a, f32x4 b) {
    short8 r;
    r[0] = (short)f2bf(a[0]); r[1] = (short)f2bf(a[1]);
    r[2] = (short)f2bf(a[2]); r[3] = (short)f2bf(a[3]);
    r[4] = (short)f2bf(b[0]); r[5] = (short)f2bf(b[1]);
    r[6] = (short)f2bf(b[2]); r[7] = (short)f2bf(b[3]);
    return r;
}

// Gather one weight matrix's 4 kt-fragments (32 strided loads, burst-issued,
// then packed). Bounded live range: 32 f32 temps.
__device__ __forceinline__ void gather_mat(const float* __restrict__ Wp, int lg, short8* out4) {
    float tv[32];
#pragma unroll
    for (int x = 0; x < 32; ++x) {
        const int kt = x >> 3, i = x & 7;
        tv[x] = Wp[(kt * 32 + lg * 8 + i) * 64];
    }
#pragma unroll
    for (int kt = 0; kt < 4; ++kt) {
        short8 r;
#pragma unroll
        for (int i = 0; i < 8; ++i) r[i] = (short)f2bf(tv[kt * 8 + i]);
        out4[kt] = r;
    }
}

// Single kernel. 4 graphs per 256-thread block (4 waves), grid = B/4.
// Order: issue HBM loads (nodes/glob/dock) -> W1 gather in 3 bursts (L2) ->
// pack+stage -> barrier -> MFMA -> spill (separate LDS region, no barrier) ->
// barrier -> stage 2. Two barriers total, 30KB LDS, 4 blocks/CU.
__global__ __launch_bounds__(256, 4) void dock_main(
    const float* __restrict__ nodes,   // [B*64,128]
    const float* __restrict__ glob,    // [B,128]
    const int*   __restrict__ dock,    // [B,64]
    const float* __restrict__ W1,      // [384,64]
    const float* __restrict__ b1,      // [64]
    const float* __restrict__ b2,      // [1]
    const float* __restrict__ W2,      // [64]
    float* __restrict__ out)           // [B,64]
{
    __shared__ __align__(16) unsigned char gA[32 * 256];   // bf16, swizzled units
    __shared__ __align__(16) unsigned char gGl[16 * 256];  // bf16, rows 4..15 zero
    __shared__ float sPQ[32][132];
    __shared__ float sA[4][68];

    const int t    = threadIdx.x;
    const int lane = t & 63;
    const int w    = __builtin_amdgcn_readfirstlane(t >> 6);
    const int b0   = blockIdx.x * 4;
    const int lr   = lane & 15, lg = lane >> 4;

    // ---- 1. issue HBM loads first (longest latency)
    const int sr = t >> 3, sc0 = (t & 7) * 16;                 // node staging coords
    const f32x4* ns4 = (const f32x4*)(nodes + ((size_t)(b0 + (sr >> 3)) * 64 + (sr & 7)) * 128 + sc0);
    const f32x4 nf0 = ns4[0], nf1 = ns4[1], nf2 = ns4[2], nf3 = ns4[3];

    const int gr = t >> 4, gc0 = (t & 15) * 8;                 // glob staging coords
    f32x4 gf0 = (f32x4)0.f, gf1 = (f32x4)0.f;
    if (gr < 4) {
        const f32x4* gs4 = (const f32x4*)(glob + (size_t)(b0 + gr) * 128 + gc0);
        gf0 = gs4[0]; gf1 = gs4[1];
    }
    const int idx   = (b0 + w) * 64 + lane;
    const int dmask = dock[idx];
    const float b1v = b1[w * 16 + lr];
    const float b2v = b2[0];

    // ---- 2. W1 gather, 3 bursts of 32 (L2-hot, 16-lane-coalesced 64B segs)
    const int n0 = w * 32 + lr;
    const int n1 = n0 + 16;
    const float* Wp0 = (n0 < 64) ? W1 + 128 * 64 + n0 : W1 + 256 * 64 + (n0 - 64);
    const float* Wp1 = (n1 < 64) ? W1 + 128 * 64 + n1 : W1 + 256 * 64 + (n1 - 64);
    const float* Wpg = W1 + (w * 16 + lr);

    short8 wf[12];                       // [0..3]=bq0, [4..7]=bq1, [8..11]=bg
    gather_mat(Wp0, lg, wf);
    gather_mat(Wp1, lg, wf + 4);
    gather_mat(Wpg, lg, wf + 8);

    // ---- 3. pack + stage A-operands to LDS (swizzled units)
    {
        const int u0 = sc0 >> 3;
        *(short8*)(gA + sr * 256 + ((u0 ^ (sr & 7)) << 4))       = pack2(nf0, nf1);
        *(short8*)(gA + sr * 256 + (((u0 + 1) ^ (sr & 7)) << 4)) = pack2(nf2, nf3);
        short8 gv = (short8)0;
        if (gr < 4) gv = pack2(gf0, gf1);
        *(short8*)(gGl + gr * 256 + (((gc0 >> 3) ^ (gr & 7)) << 4)) = gv;
    }
    __syncthreads();   // barrier 1: staging visible to all waves

    // ---- 4. MFMA: PQ[32x128] = G x W1ij^T ; A[16x64] = Gl x W1g^T
    f32x4 acc00 = (f32x4)0.f, acc01 = (f32x4)0.f;
    f32x4 acc10 = (f32x4)0.f, acc11 = (f32x4)0.f;
    f32x4 accA  = (f32x4)0.f;
#pragma unroll
    for (int kt = 0; kt < 4; ++kt) {
        const int sw = ((kt * 4 + lg) ^ (lr & 7)) << 4;
        short8 aG0 = *(const short8*)(gA + lr * 256 + sw);
        short8 aG1 = *(const short8*)(gA + (16 + lr) * 256 + sw);
        short8 aGl = *(const short8*)(gGl + lr * 256 + sw);
        acc00 = MFMA16(aG0, wf[kt],     acc00);
        acc01 = MFMA16(aG0, wf[4 + kt], acc01);
        acc10 = MFMA16(aG1, wf[kt],     acc10);
        acc11 = MFMA16(aG1, wf[4 + kt], acc11);
        accA  = MFMA16(aGl, wf[8 + kt], accA);
    }

    // ---- 5. spill C fragments (separate region -> no barrier before)
    // C layout: C[row=(lane>>4)*4+r][col=lane&15]
#pragma unroll
    for (int r = 0; r < 4; ++r) {
        sPQ[lg * 4 + r][w * 32 + lr]           = acc00[r];
        sPQ[lg * 4 + r][w * 32 + 16 + lr]      = acc01[r];
        sPQ[16 + lg * 4 + r][w * 32 + lr]      = acc10[r];
        sPQ[16 + lg * 4 + r][w * 32 + 16 + lr] = acc11[r];
    }
    if (lg == 0) {
#pragma unroll
        for (int r = 0; r < 4; ++r)
            sA[r][w * 16 + lr] = accA[r] + b1v;   // graph r, col w*16+lr (b1 folded)
    }
    __syncthreads();   // barrier 2: spill -> cross-wave stage 2

    // ---- 6. stage 2: wave w -> graph b0+w; lane p=(i,j)
    const int i = lane >> 3, j = lane & 7;
    const float* aRow = &sA[w][0];
    const float* pRow = &sPQ[w * 8 + i][0];       // P = cols [0,64)
    const float* qRow = &sPQ[w * 8 + j][64];      // Q = cols [64,128)

    float s = 0.f;
#pragma unroll
    for (int kk = 0; kk < 64; kk += 4) {
        f32x4 a4 = *(const f32x4*)(aRow + kk);
        f32x4 p4 = *(const f32x4*)(pRow + kk);
        f32x4 q4 = *(const f32x4*)(qRow + kk);
        f32x4 w4 = *(const f32x4*)(W2 + kk);      // uniform -> scalar load
#pragma unroll
        for (int u = 0; u < 4; ++u) {
            float h = a4[u] + p4[u] + q4[u];      // b1 already in A
            h = fmaxf(h, 0.f);
            s = fmaf(h, w4[u], s);
        }
    }
    s += b2v;

    out[idx] = ((i != j) && (dmask != 0)) ? s : NEGV;
}

extern "C" void kernel_launch(void* const* d_in, const int* in_sizes, int n_in,
                              void* d_out, int out_size, void* d_ws, size_t ws_size,
                              hipStream_t stream) {
    const float* nodes = (const float*)d_in[0];
    const float* glob  = (const float*)d_in[1];
    // d_in[2] group_mask_nodes, d_in[3] batch: unused (rows sorted, 8 group rows/graph)
    const int*   dock  = (const int*)d_in[4];
    const float* W1    = (const float*)d_in[5];
    const float* b1    = (const float*)d_in[6];
    const float* W2    = (const float*)d_in[7];
    const float* b2    = (const float*)d_in[8];
    float* out = (float*)d_out;

    const int B = in_sizes[1] / 128;   // 4096
    dock_main<<<dim3(B / 4), dim3(256), 0, stream>>>(
        nodes, glob, dock, W1, b1, b2, W2, out);
}

// Round 7
// 14.441 us; speedup vs baseline: 1.3104x; 1.0502x over previous
//
#include <hip/hip_runtime.h>
#include <hip/hip_bf16.h>

#define NEGV (-1e9f)

typedef __attribute__((ext_vector_type(8))) short short8;
typedef __attribute__((ext_vector_type(4))) float f32x4;

#define MFMA16(a, b, c) __builtin_amdgcn_mfma_f32_16x16x32_bf16(a, b, c, 0, 0, 0)

// Raw barrier with LDS-only drain: our in-flight global loads (vmcnt) survive.
// (__syncthreads would emit s_waitcnt vmcnt(0) and stall on prefetched loads.)
#define BAR_LDS() do { \
    asm volatile("s_waitcnt lgkmcnt(0)" ::: "memory"); \
    __builtin_amdgcn_s_barrier(); \
    asm volatile("" ::: "memory"); \
} while (0)

__device__ __forceinline__ unsigned short f2bf(float x) {
    union { __hip_bfloat16 h; unsigned short u; } c;
    c.h = __float2bfloat16(x);
    return c.u;
}

__device__ __forceinline__ short8 pack2(f32x4 a, f32x4 b) {
    short8 r;
    r[0] = (short)f2bf(a[0]); r[1] = (short)f2bf(a[1]);
    r[2] = (short)f2bf(a[2]); r[3] = (short)f2bf(a[3]);
    r[4] = (short)f2bf(b[0]); r[5] = (short)f2bf(b[1]);
    r[6] = (short)f2bf(b[2]); r[7] = (short)f2bf(b[3]);
    return r;
}

// 32 burst-issued strided loads (L2-hot), then pack 4 kt-fragments.
__device__ __forceinline__ void gather_mat(const float* __restrict__ Wp, int lg, short8* out4) {
    float tv[32];
#pragma unroll
    for (int x = 0; x < 32; ++x) {
        const int kt = x >> 3, i = x & 7;
        tv[x] = Wp[(kt * 32 + lg * 8 + i) * 64];
    }
#pragma unroll
    for (int kt = 0; kt < 4; ++kt) {
        short8 r;
#pragma unroll
        for (int i = 0; i < 8; ++i) r[i] = (short)f2bf(tv[kt * 8 + i]);
        out4[kt] = r;
    }
}

struct Acc { f32x4 a00, a01, a10, a11, aA; };

__device__ __forceinline__ Acc mfma_set(const unsigned char* gAb, const unsigned char* gGlb,
                                        const short8* wf, int lr, int lg) {
    Acc c;
    c.a00 = (f32x4)0.f; c.a01 = (f32x4)0.f; c.a10 = (f32x4)0.f; c.a11 = (f32x4)0.f; c.aA = (f32x4)0.f;
#pragma unroll
    for (int kt = 0; kt < 4; ++kt) {
        const int sw = ((kt * 4 + lg) ^ (lr & 7)) << 4;
        short8 aG0 = *(const short8*)(gAb + lr * 256 + sw);
        short8 aG1 = *(const short8*)(gAb + (16 + lr) * 256 + sw);
        short8 aGl = *(const short8*)(gGlb + lr * 256 + sw);
        c.a00 = MFMA16(aG0, wf[kt],     c.a00);
        c.a01 = MFMA16(aG0, wf[4 + kt], c.a01);
        c.a10 = MFMA16(aG1, wf[kt],     c.a10);
        c.a11 = MFMA16(aG1, wf[4 + kt], c.a11);
        c.aA  = MFMA16(aGl, wf[8 + kt], c.aA);
    }
    return c;
}

__device__ __forceinline__ void spill_set(const Acc& c, float (*sPQ)[132], float (*sA)[68],
                                          int w, int lr, int lg, float b1v) {
    // C layout: C[row=(lane>>4)*4+r][col=lane&15]
#pragma unroll
    for (int r = 0; r < 4; ++r) {
        sPQ[lg * 4 + r][w * 32 + lr]           = c.a00[r];
        sPQ[lg * 4 + r][w * 32 + 16 + lr]      = c.a01[r];
        sPQ[16 + lg * 4 + r][w * 32 + lr]      = c.a10[r];
        sPQ[16 + lg * 4 + r][w * 32 + 16 + lr] = c.a11[r];
    }
    if (lg == 0) {
#pragma unroll
        for (int r = 0; r < 4; ++r) sA[r][w * 16 + lr] = c.aA[r] + b1v;
    }
}

__device__ __forceinline__ float stage2(const float (*sPQ)[132], const float (*sA)[68],
                                        const float* __restrict__ W2, int w, int lane) {
    const int i = lane >> 3, j = lane & 7;
    const float* aRow = &sA[w][0];
    const float* pRow = &sPQ[w * 8 + i][0];
    const float* qRow = &sPQ[w * 8 + j][64];
    float s = 0.f;
#pragma unroll
    for (int kk = 0; kk < 64; kk += 4) {
        f32x4 a4 = *(const f32x4*)(aRow + kk);
        f32x4 p4 = *(const f32x4*)(pRow + kk);
        f32x4 q4 = *(const f32x4*)(qRow + kk);
        f32x4 w4 = *(const f32x4*)(W2 + kk);
#pragma unroll
        for (int u = 0; u < 4; ++u) {
            float h = a4[u] + p4[u] + q4[u];   // b1 folded into A
            h = fmaxf(h, 0.f);
            s = fmaf(h, w4[u], s);
        }
    }
    return s;
}

// 512 blocks x 256 threads; each block: 8 graphs as two pipelined sets of 4.
// Weights gathered ONCE per block; set-1 HBM loads in flight across raw
// barriers while set-0 computes. 42.5KB LDS -> 2 blocks/CU (one round).
__global__ __launch_bounds__(256, 2) void dock_main(
    const float* __restrict__ nodes,   // [B*64,128]
    const float* __restrict__ glob,    // [B,128]
    const int*   __restrict__ dock,    // [B,64]
    const float* __restrict__ W1,      // [384,64]
    const float* __restrict__ b1,      // [64]
    const float* __restrict__ b2,      // [1]
    const float* __restrict__ W2,      // [64]
    float* __restrict__ out)           // [B,64]
{
    __shared__ __align__(16) unsigned char gA[2][8192];   // bf16 staging, swizzled
    __shared__ __align__(16) unsigned char gGl[2][4096];
    __shared__ float sPQ[32][132];                        // shared spill (reused per set)
    __shared__ float sA[4][68];

    const int t    = threadIdx.x;
    const int lane = t & 63;
    const int w    = __builtin_amdgcn_readfirstlane(t >> 6);
    const int lr   = lane & 15, lg = lane >> 4;
    const int b0   = blockIdx.x * 8;

    const int sr = t >> 3, sc0 = (t & 7) * 16;   // node staging coords
    const int gr = t >> 4, gc0 = (t & 15) * 8;   // glob staging coords
    const int u0 = sc0 >> 3;

    // ---- 1. issue S0 HBM loads
    const f32x4* ns0 = (const f32x4*)(nodes + ((size_t)(b0 + (sr >> 3)) * 64 + (sr & 7)) * 128 + sc0);
    f32x4 n0a = ns0[0], n0b = ns0[1], n0c = ns0[2], n0d = ns0[3];
    f32x4 g0a = (f32x4)0.f, g0b = (f32x4)0.f;
    if (gr < 4) {
        const f32x4* gs = (const f32x4*)(glob + (size_t)(b0 + gr) * 128 + gc0);
        g0a = gs[0]; g0b = gs[1];
    }
    const int idx0 = (b0 + w) * 64 + lane;
    const int dm0  = dock[idx0];
    const float b1v = b1[w * 16 + lr];
    const float b2v = b2[0];

    // ---- 2. W1 gather (once per block), 3 bursts of 32
    const int n0 = w * 32 + lr;
    const int n1 = n0 + 16;
    const float* Wp0 = (n0 < 64) ? W1 + 128 * 64 + n0 : W1 + 256 * 64 + (n0 - 64);
    const float* Wp1 = (n1 < 64) ? W1 + 128 * 64 + n1 : W1 + 256 * 64 + (n1 - 64);
    const float* Wpg = W1 + (w * 16 + lr);
    short8 wf[12];
    gather_mat(Wp0, lg, wf);
    gather_mat(Wp1, lg, wf + 4);
    gather_mat(Wpg, lg, wf + 8);

    // ---- 3. issue S1 HBM loads (hidden under S0 compute, survive raw barriers)
    const f32x4* ns1 = (const f32x4*)(nodes + ((size_t)(b0 + 4 + (sr >> 3)) * 64 + (sr & 7)) * 128 + sc0);
    f32x4 n1a = ns1[0], n1b = ns1[1], n1c = ns1[2], n1d = ns1[3];
    f32x4 g1a = (f32x4)0.f, g1b = (f32x4)0.f;
    if (gr < 4) {
        const f32x4* gs = (const f32x4*)(glob + (size_t)(b0 + 4 + gr) * 128 + gc0);
        g1a = gs[0]; g1b = gs[1];
    }
    const int idx1 = (b0 + 4 + w) * 64 + lane;
    const int dm1  = dock[idx1];

    // ---- 4. pack + stage S0
    *(short8*)(gA[0] + sr * 256 + ((u0 ^ (sr & 7)) << 4))       = pack2(n0a, n0b);
    *(short8*)(gA[0] + sr * 256 + (((u0 + 1) ^ (sr & 7)) << 4)) = pack2(n0c, n0d);
    {
        short8 gv = (short8)0;
        if (gr < 4) gv = pack2(g0a, g0b);
        *(short8*)(gGl[0] + gr * 256 + (((gc0 >> 3) ^ (gr & 7)) << 4)) = gv;
    }
    BAR_LDS();   // bar1: S0 staging visible (S1 global loads stay in flight)

    // ---- 5. MFMA S0 + spill
    Acc c0 = mfma_set(gA[0], gGl[0], wf, lr, lg);
    spill_set(c0, sPQ, sA, w, lr, lg, b1v);
    BAR_LDS();   // bar2: S0 spill visible

    // ---- 6. pack + stage S1 (separate region; vmcnt wait lands here)
    *(short8*)(gA[1] + sr * 256 + ((u0 ^ (sr & 7)) << 4))       = pack2(n1a, n1b);
    *(short8*)(gA[1] + sr * 256 + (((u0 + 1) ^ (sr & 7)) << 4)) = pack2(n1c, n1d);
    {
        short8 gv = (short8)0;
        if (gr < 4) gv = pack2(g1a, g1b);
        *(short8*)(gGl[1] + gr * 256 + (((gc0 >> 3) ^ (gr & 7)) << 4)) = gv;
    }

    // ---- 7. stage 2 for S0 + store
    {
        const int i = lane >> 3, j = lane & 7;
        float s = stage2(sPQ, sA, W2, w, lane) + b2v;
        out[idx0] = ((i != j) && (dm0 != 0)) ? s : NEGV;
    }
    BAR_LDS();   // bar3: S1 staging visible AND sPQ reads retired

    // ---- 8. MFMA S1 + spill
    Acc c1 = mfma_set(gA[1], gGl[1], wf, lr, lg);
    spill_set(c1, sPQ, sA, w, lr, lg, b1v);
    BAR_LDS();   // bar4: S1 spill visible

    // ---- 9. stage 2 for S1 + store
    {
        const int i = lane >> 3, j = lane & 7;
        float s = stage2(sPQ, sA, W2, w, lane) + b2v;
        out[idx1] = ((i != j) && (dm1 != 0)) ? s : NEGV;
    }
}

extern "C" void kernel_launch(void* const* d_in, const int* in_sizes, int n_in,
                              void* d_out, int out_size, void* d_ws, size_t ws_size,
                              hipStream_t stream) {
    const float* nodes = (const float*)d_in[0];
    const float* glob  = (const float*)d_in[1];
    // d_in[2] group_mask_nodes, d_in[3] batch: unused (rows sorted, 8 group rows/graph)
    const int*   dock  = (const int*)d_in[4];
    const float* W1    = (const float*)d_in[5];
    const float* b1    = (const float*)d_in[6];
    const float* W2    = (const float*)d_in[7];
    const float* b2    = (const float*)d_in[8];
    float* out = (float*)d_out;

    const int B = in_sizes[1] / 128;   // 4096
    dock_main<<<dim3(B / 8), dim3(256), 0, stream>>>(
        nodes, glob, dock, W1, b1, b2, W2, out);
}